// Round 5
// baseline (320.005 us; speedup 1.0000x reference)
//
#include <hip/hip_runtime.h>
#include <math.h>

#define L    1024
#define D    256
#define NCH  3
#define HEADS 32      // B*N
#define EDIM 112
#define BATCH 4

typedef __bf16 bf8_t __attribute__((ext_vector_type(8)));
typedef float  f4_t  __attribute__((ext_vector_type(4)));

// RNE float->bf16
__device__ inline unsigned short f2bf(float x) {
    unsigned u = __float_as_uint(x);
    u += 0x7FFFu + ((u >> 16) & 1u);
    return (unsigned short)(u >> 16);
}
__device__ inline float bf2f(unsigned short h) {
    return __uint_as_float(((unsigned)h) << 16);
}

// ---------------- PE kernels (fp32; err ~1e-5 vs threshold 0.1) ------------
__global__ void pe_d_kernel(float* __restrict__ pe_d) {
    int idx = blockIdx.x * blockDim.x + threadIdx.x;
    if (idx >= L * D) return;
    int l = idx >> 8, i = idx & (D - 1);
    float expo = (float)(i & ~1) * (1.0f / (float)D);
    float ang = (float)l * __powf(10000.0f, -expo);
    pe_d[idx] = (i & 1) ? cosf(ang) : sinf(ang);
}

__global__ void edge_kernel(const float* __restrict__ edge, float* __restrict__ out) {
    int idx = blockIdx.x * blockDim.x + threadIdx.x;
    if (idx >= BATCH * L * EDIM) return;
    int i = idx % EDIM;
    int l = (idx / EDIM) % L;
    float expo = (float)(i & ~1) * (1.0f / (float)EDIM);
    float ang = (float)l * __powf(10000.0f, -expo);
    out[idx] = edge[idx] + ((i & 1) ? cosf(ang) : sinf(ang));
}

// xi + pe(n=3), computed once into xsb [32][1024][3]
__global__ void xs_kernel(const float* __restrict__ xi, float* __restrict__ xsb) {
    int idx = blockIdx.x * blockDim.x + threadIdx.x;
    if (idx >= HEADS * L * NCH) return;
    int c = idx % 3;
    int l = (idx / 3) & (L - 1);
    float ang = (c == 2) ? (float)l * 0.0021544347f : (float)l;  // 10000^(-2/3)
    float pe = (c == 1) ? cosf(ang) : sinf(ang);
    xsb[idx] = xi[idx] + pe;
}

// ---------------- QKV projection via split-bf16 MFMA (2-term) --------------
// q,k: C^T = Wh*(Xh+Xl)^T  -> packed b64 stores along e (hi only)
// v:   C   = (Xh+Xl)*Wh^T  -> written tile-major vt[head][ktile32][e][key31]
__global__ __launch_bounds__(256) void qkv_mfma(
    const float* __restrict__ theta, const float* __restrict__ pe_d,
    const float* __restrict__ Wq, const float* __restrict__ Wk, const float* __restrict__ Wv,
    unsigned short* __restrict__ qh, unsigned short* __restrict__ kh,
    unsigned short* __restrict__ vt)
{
    __shared__ unsigned short XsH[128][40], XsL[128][40], WsH[128][40];

    int tid = threadIdx.x;
    int w = tid >> 6, lane = tid & 63;
    int quad = lane >> 4, l16 = lane & 15;
    int aoff = (w & 1) * 64, boff = (w >> 1) * 64;
    int rowBase = blockIdx.y * 128;
    int wsel = blockIdx.x >> 1;
    int eBase = (blockIdx.x & 1) * 128;
    const float* W = (wsel == 0) ? Wq : (wsel == 1) ? Wk : Wv;

    f4_t acc[4][4];
    #pragma unroll
    for (int mi = 0; mi < 4; mi++)
        #pragma unroll
        for (int ni = 0; ni < 4; ni++) acc[mi][ni] = (f4_t){0.f, 0.f, 0.f, 0.f};

    int sr = tid >> 1;
    int ks = (tid & 1) * 16;

    for (int kt = 0; kt < 8; kt++) {
        int k0 = kt * 32 + ks;
        __syncthreads();
        {
            union { unsigned short us[16]; float4 f4[2]; } hi, lo;
            const float* tp = &theta[(size_t)(rowBase + sr) * D + k0];
            const float* pp = &pe_d[(size_t)((rowBase + sr) & (L - 1)) * D + k0];
            #pragma unroll
            for (int j = 0; j < 4; j++) {
                float4 tv = reinterpret_cast<const float4*>(tp)[j];
                float4 pv = reinterpret_cast<const float4*>(pp)[j];
                float xs[4] = {tv.x + pv.x, tv.y + pv.y, tv.z + pv.z, tv.w + pv.w};
                #pragma unroll
                for (int q = 0; q < 4; q++) {
                    unsigned short h = f2bf(xs[q]);
                    hi.us[j * 4 + q] = h;
                    lo.us[j * 4 + q] = f2bf(xs[q] - bf2f(h));
                }
            }
            *reinterpret_cast<float4*>(&XsH[sr][ks]) = hi.f4[0];
            *reinterpret_cast<float4*>(&XsH[sr][ks + 8]) = hi.f4[1];
            *reinterpret_cast<float4*>(&XsL[sr][ks]) = lo.f4[0];
            *reinterpret_cast<float4*>(&XsL[sr][ks + 8]) = lo.f4[1];

            const float* wp = &W[(size_t)(eBase + sr) * D + k0];
            #pragma unroll
            for (int j = 0; j < 4; j++) {
                float4 wv = reinterpret_cast<const float4*>(wp)[j];
                float xs[4] = {wv.x, wv.y, wv.z, wv.w};
                #pragma unroll
                for (int q = 0; q < 4; q++) hi.us[j * 4 + q] = f2bf(xs[q]);
            }
            *reinterpret_cast<float4*>(&WsH[sr][ks]) = hi.f4[0];
            *reinterpret_cast<float4*>(&WsH[sr][ks + 8]) = hi.f4[1];
        }
        __syncthreads();

        if (wsel < 2) {
            bf8_t aw[4];
            #pragma unroll
            for (int mi = 0; mi < 4; mi++)
                aw[mi] = *reinterpret_cast<const bf8_t*>(&WsH[aoff + mi * 16 + l16][quad * 8]);
            #pragma unroll
            for (int ni = 0; ni < 4; ni++) {
                bf8_t bxh = *reinterpret_cast<const bf8_t*>(&XsH[boff + ni * 16 + l16][quad * 8]);
                bf8_t bxl = *reinterpret_cast<const bf8_t*>(&XsL[boff + ni * 16 + l16][quad * 8]);
                #pragma unroll
                for (int mi = 0; mi < 4; mi++) {
                    acc[mi][ni] = __builtin_amdgcn_mfma_f32_16x16x32_bf16(aw[mi], bxh, acc[mi][ni], 0, 0, 0);
                    acc[mi][ni] = __builtin_amdgcn_mfma_f32_16x16x32_bf16(aw[mi], bxl, acc[mi][ni], 0, 0, 0);
                }
            }
        } else {
            bf8_t axh[4], axl[4];
            #pragma unroll
            for (int mi = 0; mi < 4; mi++) {
                axh[mi] = *reinterpret_cast<const bf8_t*>(&XsH[aoff + mi * 16 + l16][quad * 8]);
                axl[mi] = *reinterpret_cast<const bf8_t*>(&XsL[aoff + mi * 16 + l16][quad * 8]);
            }
            #pragma unroll
            for (int ni = 0; ni < 4; ni++) {
                bf8_t bw = *reinterpret_cast<const bf8_t*>(&WsH[boff + ni * 16 + l16][quad * 8]);
                #pragma unroll
                for (int mi = 0; mi < 4; mi++) {
                    acc[mi][ni] = __builtin_amdgcn_mfma_f32_16x16x32_bf16(axh[mi], bw, acc[mi][ni], 0, 0, 0);
                    acc[mi][ni] = __builtin_amdgcn_mfma_f32_16x16x32_bf16(axl[mi], bw, acc[mi][ni], 0, 0, 0);
                }
            }
        }
    }

    if (wsel < 2) {
        float scale = (wsel == 0) ? 0.0625f : 1.0f;  // fold 1/sqrt(d) into q
        unsigned short* dh = (wsel == 0) ? qh : kh;
        #pragma unroll
        for (int mi = 0; mi < 4; mi++) {
            #pragma unroll
            for (int ni = 0; ni < 4; ni++) {
                int e0 = eBase + aoff + mi * 16 + quad * 4;
                size_t row = rowBase + boff + ni * 16 + l16;
                union { unsigned short us[4]; unsigned long long u; } ph;
                #pragma unroll
                for (int r = 0; r < 4; r++) ph.us[r] = f2bf(acc[mi][ni][r] * scale);
                *reinterpret_cast<unsigned long long*>(&dh[row * D + e0]) = ph.u;
            }
        }
    } else {
        #pragma unroll
        for (int mi = 0; mi < 4; mi++) {
            #pragma unroll
            for (int ni = 0; ni < 4; ni++) {
                int row0 = rowBase + aoff + mi * 16 + quad * 4;
                int e = eBase + boff + ni * 16 + l16;
                int head = row0 >> 10, kb = (row0 & 1023) >> 5, kk = row0 & 31;
                union { unsigned short us[4]; unsigned long long u; } pk;
                #pragma unroll
                for (int r = 0; r < 4; r++) pk.us[r] = f2bf(acc[mi][ni][r]);
                *reinterpret_cast<unsigned long long*>(
                    &vt[((size_t)(head * 32 + kb)) * 8192 + (size_t)e * 32 + kk]) = pk.u;
            }
        }
    }
}

// ---------------- K-split MFMA flash attention (flash-decoding style) ------
// Block = (head, pair u/63-u). 4 waves strided over kt tiles, private online
// softmax; pairwise LDS tree combine at the end of each half.
__global__ __launch_bounds__(256, 3) void attn_v4(
    const unsigned short* __restrict__ qh, const unsigned short* __restrict__ kh,
    const unsigned short* __restrict__ vt, float* __restrict__ hout)
{
    __shared__ unsigned short Pb[4][16 * 40];
    __shared__ float Ob[2][16][268];
    __shared__ float MLb[128];

    int tid = threadIdx.x;
    int w = tid >> 6, lane = tid & 63;
    int quad = lane >> 4, l16 = lane & 15;
    int b = blockIdx.x;
    int head = b & 31, p = b >> 5;          // same head -> same XCD (b%8 = head%8)
    size_t hb = (size_t)head * (L * D);
    const unsigned short* vth = vt + (size_t)head * (32 * 8192);
    unsigned short* Pw = Pb[w];

    #pragma unroll 1
    for (int half = 0; half < 2; half++) {
        int u = half ? (63 - p) : p;         // pair sums to 34 kt-tiles
        int q_g = u * 16 + l16;

        bf8_t qf[8];
        {
            const unsigned short* ph = qh + hb + (size_t)q_g * D + quad * 8;
            #pragma unroll
            for (int c = 0; c < 8; c++) qf[c] = *reinterpret_cast<const bf8_t*>(ph + c * 32);
        }

        f4_t acc[16];
        #pragma unroll
        for (int i = 0; i < 16; i++) acc[i] = (f4_t){0.f, 0.f, 0.f, 0.f};
        float mrun = -1e30f, lrun = 0.f;

        int nkt = (u >> 1) + 1;
        for (int kt = w; kt < nkt; kt += 4) {
            int kBase = kt * 32;

            f4_t s[2];
            #pragma unroll
            for (int t = 0; t < 2; t++) {
                s[t] = (f4_t){0.f, 0.f, 0.f, 0.f};
                const unsigned short* kp =
                    kh + hb + (size_t)(kBase + t * 16 + l16) * D + quad * 8;
                bf8_t kf[8];
                #pragma unroll
                for (int c = 0; c < 8; c++) kf[c] = *reinterpret_cast<const bf8_t*>(kp + c * 32);
                #pragma unroll
                for (int c = 0; c < 8; c++)
                    s[t] = __builtin_amdgcn_mfma_f32_16x16x32_bf16(kf[c], qf[c], s[t], 0, 0, 0);
            }

            // V fragments issued early; latency covered by the softmax below
            const unsigned short* vp = vth + (size_t)kt * 8192 + l16 * 32 + quad * 8;
            bf8_t vf[16];
            #pragma unroll
            for (int dt = 0; dt < 16; dt++)
                vf[dt] = *reinterpret_cast<const bf8_t*>(vp + dt * 512);

            float pv[2][4];
            float tm = -1e30f;
            #pragma unroll
            for (int t = 0; t < 2; t++)
                #pragma unroll
                for (int r = 0; r < 4; r++) {
                    int key = kBase + t * 16 + quad * 4 + r;
                    float sv = (key <= q_g) ? s[t][r] : -1e30f;
                    s[t][r] = sv;
                    tm = fmaxf(tm, sv);
                }
            tm = fmaxf(tm, __shfl_xor(tm, 16));
            tm = fmaxf(tm, __shfl_xor(tm, 32));
            float mnew = fmaxf(mrun, tm);
            float alpha = __expf(mrun - mnew);
            mrun = mnew;
            float ts = 0.f;
            #pragma unroll
            for (int t = 0; t < 2; t++)
                #pragma unroll
                for (int r = 0; r < 4; r++) {
                    float pe = __expf(s[t][r] - mnew);
                    pv[t][r] = pe;
                    ts += pe;
                }
            ts += __shfl_xor(ts, 16);
            ts += __shfl_xor(ts, 32);
            lrun = lrun * alpha + ts;
            if (__any(alpha != 1.0f)) {
                #pragma unroll
                for (int dt = 0; dt < 16; dt++) acc[dt] *= alpha;
            }

            #pragma unroll
            for (int t = 0; t < 2; t++) {
                union { unsigned short us[4]; unsigned long long u; } pk;
                #pragma unroll
                for (int r = 0; r < 4; r++) pk.us[r] = f2bf(pv[t][r]);
                *reinterpret_cast<unsigned long long*>(&Pw[l16 * 40 + t * 16 + quad * 4]) = pk.u;
            }
            asm volatile("s_waitcnt lgkmcnt(0)" ::: "memory");
            bf8_t pf = *reinterpret_cast<const bf8_t*>(&Pw[l16 * 40 + quad * 8]);
            #pragma unroll
            for (int dt = 0; dt < 16; dt++)
                acc[dt] = __builtin_amdgcn_mfma_f32_16x16x32_bf16(vf[dt], pf, acc[dt], 0, 0, 0);
        }

        // ---- combine 4 wave-partials ----
        if (quad == 0) { MLb[w * 32 + l16] = mrun; MLb[w * 32 + 16 + l16] = lrun; }
        __syncthreads();
        float m0 = MLb[l16],      l0 = MLb[16 + l16];
        float m1 = MLb[32 + l16], l1 = MLb[48 + l16];
        float m2 = MLb[64 + l16], l2 = MLb[80 + l16];
        float m3 = MLb[96 + l16], l3 = MLb[112 + l16];
        float mg = fmaxf(fmaxf(m0, m1), fmaxf(m2, m3));
        float lg = l0 * __expf(m0 - mg) + l1 * __expf(m1 - mg)
                 + l2 * __expf(m2 - mg) + l3 * __expf(m3 - mg);
        float scale = __expf(mrun - mg);
        #pragma unroll
        for (int dt = 0; dt < 16; dt++) acc[dt] *= scale;

        if (w >= 2) {
            float* ob = &Ob[w - 2][l16][quad * 4];
            #pragma unroll
            for (int dt = 0; dt < 16; dt++)
                *reinterpret_cast<float4*>(ob + dt * 16) =
                    (float4){acc[dt][0], acc[dt][1], acc[dt][2], acc[dt][3]};
        }
        __syncthreads();
        if (w < 2) {
            const float* ob = &Ob[w][l16][quad * 4];
            #pragma unroll
            for (int dt = 0; dt < 16; dt++) {
                float4 v = *reinterpret_cast<const float4*>(ob + dt * 16);
                acc[dt][0] += v.x; acc[dt][1] += v.y;
                acc[dt][2] += v.z; acc[dt][3] += v.w;
            }
        }
        __syncthreads();
        if (w == 1) {
            float* ob = &Ob[0][l16][quad * 4];
            #pragma unroll
            for (int dt = 0; dt < 16; dt++)
                *reinterpret_cast<float4*>(ob + dt * 16) =
                    (float4){acc[dt][0], acc[dt][1], acc[dt][2], acc[dt][3]};
        }
        __syncthreads();
        if (w == 0) {
            const float* ob = &Ob[0][l16][quad * 4];
            float inv = 1.f / lg;
            float* dst = hout + hb + (size_t)q_g * D + quad * 4;
            #pragma unroll
            for (int dt = 0; dt < 16; dt++) {
                float4 v = *reinterpret_cast<const float4*>(ob + dt * 16);
                float4 o = {(acc[dt][0] + v.x) * inv, (acc[dt][1] + v.y) * inv,
                            (acc[dt][2] + v.z) * inv, (acc[dt][3] + v.w) * inv};
                *reinterpret_cast<float4*>(dst + dt * 16) = o;
            }
        }
        __syncthreads();
    }
}

// ---------------- equivariant path: one wave per q row ---------------------
__global__ __launch_bounds__(256) void equiv_kernel(
    const float* __restrict__ xsb, float* __restrict__ xout)
{
    __shared__ float xs[L * NCH];
    int head = blockIdx.y;
    int tid = threadIdx.x;
    const float4* src = reinterpret_cast<const float4*>(xsb + (size_t)head * L * NCH);
    #pragma unroll
    for (int it = 0; it < 3; it++)
        reinterpret_cast<float4*>(xs)[tid + it * 256] = src[tid + it * 256];
    __syncthreads();

    int w = tid >> 6, lane = tid & 63;
    int q = blockIdx.x * 4 + w;
    float xq0 = xs[q * 3 + 0], xq1 = xs[q * 3 + 1], xq2 = xs[q * 3 + 2];

    float m = 0.f;
    for (int k = lane; k < q; k += 64) {
        float d0 = xq0 - xs[k * 3 + 0];
        float d1 = xq1 - xs[k * 3 + 1];
        float d2 = xq2 - xs[k * 3 + 2];
        m = fmaxf(m, d0 * d0 + d1 * d1 + d2 * d2);
    }
    #pragma unroll
    for (int off = 1; off < 64; off <<= 1) m = fmaxf(m, __shfl_xor(m, off));

    float s0 = 0.f, s1 = 0.f, s2 = 0.f, sn = 0.f;
    for (int k = lane; k < q; k += 64) {
        float d0 = xq0 - xs[k * 3 + 0];
        float d1 = xq1 - xs[k * 3 + 1];
        float d2 = xq2 - xs[k * 3 + 2];
        float wgt = __expf(d0 * d0 + d1 * d1 + d2 * d2 - m);
        sn += wgt;
        s0 += wgt * xs[k * 3 + 0];
        s1 += wgt * xs[k * 3 + 1];
        s2 += wgt * xs[k * 3 + 2];
    }
    #pragma unroll
    for (int off = 1; off < 64; off <<= 1) {
        sn += __shfl_xor(sn, off);
        s0 += __shfl_xor(s0, off);
        s1 += __shfl_xor(s1, off);
        s2 += __shfl_xor(s2, off);
    }
    float Z = sn + __expf(-m);
    float inv = 0.5f / Z;
    if (lane == 0) {
        size_t ob = (size_t)head * L * NCH + (size_t)q * NCH;
        xout[ob + 0] = xq0 + inv * (s0 - sn * xq0);
        xout[ob + 1] = xq1 + inv * (s1 - sn * xq1);
        xout[ob + 2] = xq2 + inv * (s2 - sn * xq2);
    }
}

extern "C" void kernel_launch(void* const* d_in, const int* in_sizes, int n_in,
                              void* d_out, int out_size, void* d_ws, size_t ws_size,
                              hipStream_t stream)
{
    (void)in_sizes; (void)n_in; (void)out_size; (void)ws_size;
    const float* theta = (const float*)d_in[0];
    const float* xi    = (const float*)d_in[1];
    const float* edge  = (const float*)d_in[2];
    const float* Wq    = (const float*)d_in[3];
    const float* Wk    = (const float*)d_in[4];
    const float* Wv    = (const float*)d_in[5];

    float* out  = (float*)d_out;
    float* hout = out;
    float* xout = out + 8388608;
    float* eout = out + 8388608 + 98304;

    const size_t NE = 8388608;
    unsigned short* base = (unsigned short*)d_ws;
    unsigned short* qh = base;
    unsigned short* kh = base + NE;
    unsigned short* vt = base + 2 * NE;
    float* pe_d = (float*)(base + 3 * NE);           // 1024*256 floats
    float* xsb  = pe_d + L * D;                       // 32*1024*3 floats

    pe_d_kernel<<<(L * D + 255) / 256, 256, 0, stream>>>(pe_d);
    edge_kernel<<<(BATCH * L * EDIM + 255) / 256, 256, 0, stream>>>(edge, eout);
    xs_kernel<<<(HEADS * L * NCH + 255) / 256, 256, 0, stream>>>(xi, xsb);
    equiv_kernel<<<dim3(L / 4, HEADS), 256, 0, stream>>>(xsb, xout);
    qkv_mfma<<<dim3(6, 256), 256, 0, stream>>>(theta, pe_d, Wq, Wk, Wv,
                                               qh, kh, vt);
    attn_v4<<<1024, 256, 0, stream>>>(qh, kh, vt, hout);
}

// Round 6
// 305.891 us; speedup vs baseline: 1.0461x; 1.0461x over previous
//
#include <hip/hip_runtime.h>
#include <math.h>

#define L    1024
#define D    256
#define NCH  3
#define HEADS 32      // B*N
#define EDIM 112
#define BATCH 4

typedef __bf16 bf8_t __attribute__((ext_vector_type(8)));
typedef float  f4_t  __attribute__((ext_vector_type(4)));

// RNE float->bf16
__device__ inline unsigned short f2bf(float x) {
    unsigned u = __float_as_uint(x);
    u += 0x7FFFu + ((u >> 16) & 1u);
    return (unsigned short)(u >> 16);
}
__device__ inline float bf2f(unsigned short h) {
    return __uint_as_float(((unsigned)h) << 16);
}

// ---------------- PE kernels (fp32; err ~1e-5 vs threshold 0.1) ------------
__global__ void pe_d_kernel(float* __restrict__ pe_d) {
    int idx = blockIdx.x * blockDim.x + threadIdx.x;
    if (idx >= L * D) return;
    int l = idx >> 8, i = idx & (D - 1);
    float expo = (float)(i & ~1) * (1.0f / (float)D);
    float ang = (float)l * __powf(10000.0f, -expo);
    pe_d[idx] = (i & 1) ? cosf(ang) : sinf(ang);
}

__global__ void edge_kernel(const float* __restrict__ edge, float* __restrict__ out) {
    int idx = blockIdx.x * blockDim.x + threadIdx.x;
    if (idx >= BATCH * L * EDIM) return;
    int i = idx % EDIM;
    int l = (idx / EDIM) % L;
    float expo = (float)(i & ~1) * (1.0f / (float)EDIM);
    float ang = (float)l * __powf(10000.0f, -expo);
    out[idx] = edge[idx] + ((i & 1) ? cosf(ang) : sinf(ang));
}

// xi + pe(n=3), computed once into xsb [32][1024][3]
__global__ void xs_kernel(const float* __restrict__ xi, float* __restrict__ xsb) {
    int idx = blockIdx.x * blockDim.x + threadIdx.x;
    if (idx >= HEADS * L * NCH) return;
    int c = idx % 3;
    int l = (idx / 3) & (L - 1);
    float ang = (c == 2) ? (float)l * 0.0021544347f : (float)l;  // 10000^(-2/3)
    float pe = (c == 1) ? cosf(ang) : sinf(ang);
    xsb[idx] = xi[idx] + pe;
}

// ---------------- QKV projection via split-bf16 MFMA (2-term) --------------
// q,k: C^T = Wh*(Xh+Xl)^T  -> packed b64 stores along e (hi only)
// v:   C   = (Xh+Xl)*Wh^T  -> written tile-major vt[head][ktile32][e][key31]
__global__ __launch_bounds__(256) void qkv_mfma(
    const float* __restrict__ theta, const float* __restrict__ pe_d,
    const float* __restrict__ Wq, const float* __restrict__ Wk, const float* __restrict__ Wv,
    unsigned short* __restrict__ qh, unsigned short* __restrict__ kh,
    unsigned short* __restrict__ vt)
{
    __shared__ unsigned short XsH[128][40], XsL[128][40], WsH[128][40];

    int tid = threadIdx.x;
    int w = tid >> 6, lane = tid & 63;
    int quad = lane >> 4, l16 = lane & 15;
    int aoff = (w & 1) * 64, boff = (w >> 1) * 64;
    int rowBase = blockIdx.y * 128;
    int wsel = blockIdx.x >> 1;
    int eBase = (blockIdx.x & 1) * 128;
    const float* W = (wsel == 0) ? Wq : (wsel == 1) ? Wk : Wv;

    f4_t acc[4][4];
    #pragma unroll
    for (int mi = 0; mi < 4; mi++)
        #pragma unroll
        for (int ni = 0; ni < 4; ni++) acc[mi][ni] = (f4_t){0.f, 0.f, 0.f, 0.f};

    int sr = tid >> 1;
    int ks = (tid & 1) * 16;

    for (int kt = 0; kt < 8; kt++) {
        int k0 = kt * 32 + ks;
        __syncthreads();
        {
            union { unsigned short us[16]; float4 f4[2]; } hi, lo;
            const float* tp = &theta[(size_t)(rowBase + sr) * D + k0];
            const float* pp = &pe_d[(size_t)((rowBase + sr) & (L - 1)) * D + k0];
            #pragma unroll
            for (int j = 0; j < 4; j++) {
                float4 tv = reinterpret_cast<const float4*>(tp)[j];
                float4 pv = reinterpret_cast<const float4*>(pp)[j];
                float xs[4] = {tv.x + pv.x, tv.y + pv.y, tv.z + pv.z, tv.w + pv.w};
                #pragma unroll
                for (int q = 0; q < 4; q++) {
                    unsigned short h = f2bf(xs[q]);
                    hi.us[j * 4 + q] = h;
                    lo.us[j * 4 + q] = f2bf(xs[q] - bf2f(h));
                }
            }
            *reinterpret_cast<float4*>(&XsH[sr][ks]) = hi.f4[0];
            *reinterpret_cast<float4*>(&XsH[sr][ks + 8]) = hi.f4[1];
            *reinterpret_cast<float4*>(&XsL[sr][ks]) = lo.f4[0];
            *reinterpret_cast<float4*>(&XsL[sr][ks + 8]) = lo.f4[1];

            const float* wp = &W[(size_t)(eBase + sr) * D + k0];
            #pragma unroll
            for (int j = 0; j < 4; j++) {
                float4 wv = reinterpret_cast<const float4*>(wp)[j];
                float xs[4] = {wv.x, wv.y, wv.z, wv.w};
                #pragma unroll
                for (int q = 0; q < 4; q++) hi.us[j * 4 + q] = f2bf(xs[q]);
            }
            *reinterpret_cast<float4*>(&WsH[sr][ks]) = hi.f4[0];
            *reinterpret_cast<float4*>(&WsH[sr][ks + 8]) = hi.f4[1];
        }
        __syncthreads();

        if (wsel < 2) {
            bf8_t aw[4];
            #pragma unroll
            for (int mi = 0; mi < 4; mi++)
                aw[mi] = *reinterpret_cast<const bf8_t*>(&WsH[aoff + mi * 16 + l16][quad * 8]);
            #pragma unroll
            for (int ni = 0; ni < 4; ni++) {
                bf8_t bxh = *reinterpret_cast<const bf8_t*>(&XsH[boff + ni * 16 + l16][quad * 8]);
                bf8_t bxl = *reinterpret_cast<const bf8_t*>(&XsL[boff + ni * 16 + l16][quad * 8]);
                #pragma unroll
                for (int mi = 0; mi < 4; mi++) {
                    acc[mi][ni] = __builtin_amdgcn_mfma_f32_16x16x32_bf16(aw[mi], bxh, acc[mi][ni], 0, 0, 0);
                    acc[mi][ni] = __builtin_amdgcn_mfma_f32_16x16x32_bf16(aw[mi], bxl, acc[mi][ni], 0, 0, 0);
                }
            }
        } else {
            bf8_t axh[4], axl[4];
            #pragma unroll
            for (int mi = 0; mi < 4; mi++) {
                axh[mi] = *reinterpret_cast<const bf8_t*>(&XsH[aoff + mi * 16 + l16][quad * 8]);
                axl[mi] = *reinterpret_cast<const bf8_t*>(&XsL[aoff + mi * 16 + l16][quad * 8]);
            }
            #pragma unroll
            for (int ni = 0; ni < 4; ni++) {
                bf8_t bw = *reinterpret_cast<const bf8_t*>(&WsH[boff + ni * 16 + l16][quad * 8]);
                #pragma unroll
                for (int mi = 0; mi < 4; mi++) {
                    acc[mi][ni] = __builtin_amdgcn_mfma_f32_16x16x32_bf16(axh[mi], bw, acc[mi][ni], 0, 0, 0);
                    acc[mi][ni] = __builtin_amdgcn_mfma_f32_16x16x32_bf16(axl[mi], bw, acc[mi][ni], 0, 0, 0);
                }
            }
        }
    }

    if (wsel < 2) {
        float scale = (wsel == 0) ? 0.0625f : 1.0f;  // fold 1/sqrt(d) into q
        unsigned short* dh = (wsel == 0) ? qh : kh;
        #pragma unroll
        for (int mi = 0; mi < 4; mi++) {
            #pragma unroll
            for (int ni = 0; ni < 4; ni++) {
                int e0 = eBase + aoff + mi * 16 + quad * 4;
                size_t row = rowBase + boff + ni * 16 + l16;
                union { unsigned short us[4]; unsigned long long u; } ph;
                #pragma unroll
                for (int r = 0; r < 4; r++) ph.us[r] = f2bf(acc[mi][ni][r] * scale);
                *reinterpret_cast<unsigned long long*>(&dh[row * D + e0]) = ph.u;
            }
        }
    } else {
        #pragma unroll
        for (int mi = 0; mi < 4; mi++) {
            #pragma unroll
            for (int ni = 0; ni < 4; ni++) {
                int row0 = rowBase + aoff + mi * 16 + quad * 4;
                int e = eBase + boff + ni * 16 + l16;
                int head = row0 >> 10, kb = (row0 & 1023) >> 5, kk = row0 & 31;
                union { unsigned short us[4]; unsigned long long u; } pk;
                #pragma unroll
                for (int r = 0; r < 4; r++) pk.us[r] = f2bf(acc[mi][ni][r]);
                *reinterpret_cast<unsigned long long*>(
                    &vt[((size_t)(head * 32 + kb)) * 8192 + (size_t)e * 32 + kk]) = pk.u;
            }
        }
    }
}

// ---------------- K-split MFMA flash attention, spill-free ------------------
// Block = (head, pair u/63-u). 4 waves strided over kt (mod 4), private
// online softmax; tree combine per half. No min-wave launch bound (v4's
// (256,3) forced VGPR=84 -> 79MB/dispatch scratch spill). PV chunked 2x8
// to keep peak live regs ~150.
__global__ __launch_bounds__(256) void attn_v5(
    const unsigned short* __restrict__ qh, const unsigned short* __restrict__ kh,
    const unsigned short* __restrict__ vt, float* __restrict__ hout)
{
    __shared__ unsigned short Pb[4][16 * 40];
    __shared__ float Ob[2][16][268];
    __shared__ float MLb[128];

    int tid = threadIdx.x;
    int w = tid >> 6, lane = tid & 63;
    int quad = lane >> 4, l16 = lane & 15;
    int b = blockIdx.x;
    int head = b & 31, p = b >> 5;          // same head -> same XCD (b%8 const)
    size_t hb = (size_t)head * (L * D);
    const unsigned short* vth = vt + (size_t)head * (32 * 8192);
    unsigned short* Pw = Pb[w];

    #pragma unroll 1
    for (int half = 0; half < 2; half++) {
        int u = half ? (63 - p) : p;         // pair sums to 34 kt-tiles
        int q_g = u * 16 + l16;
        int rmax = u * 16 + 15;

        bf8_t qf[8];
        {
            const unsigned short* ph = qh + hb + (size_t)q_g * D + quad * 8;
            #pragma unroll
            for (int c = 0; c < 8; c++) qf[c] = *reinterpret_cast<const bf8_t*>(ph + c * 32);
        }

        f4_t acc[16];
        #pragma unroll
        for (int i = 0; i < 16; i++) acc[i] = (f4_t){0.f, 0.f, 0.f, 0.f};
        float mrun = -1e30f, lrun = 0.f;

        int nkt = (u >> 1) + 1;
        #pragma unroll 1
        for (int kt = w; kt < nkt; kt += 4) {
            int kBase = kt * 32;

            f4_t s[2];
            {
                s[0] = (f4_t){0.f, 0.f, 0.f, 0.f};
                const unsigned short* kp = kh + hb + (size_t)(kBase + l16) * D + quad * 8;
                bf8_t kf[8];
                #pragma unroll
                for (int c = 0; c < 8; c++) kf[c] = *reinterpret_cast<const bf8_t*>(kp + c * 32);
                #pragma unroll
                for (int c = 0; c < 8; c++)
                    s[0] = __builtin_amdgcn_mfma_f32_16x16x32_bf16(kf[c], qf[c], s[0], 0, 0, 0);
            }
            if (kBase + 16 <= rmax) {        // t=1 subtile not fully masked
                s[1] = (f4_t){0.f, 0.f, 0.f, 0.f};
                const unsigned short* kp = kh + hb + (size_t)(kBase + 16 + l16) * D + quad * 8;
                bf8_t kf[8];
                #pragma unroll
                for (int c = 0; c < 8; c++) kf[c] = *reinterpret_cast<const bf8_t*>(kp + c * 32);
                #pragma unroll
                for (int c = 0; c < 8; c++)
                    s[1] = __builtin_amdgcn_mfma_f32_16x16x32_bf16(kf[c], qf[c], s[1], 0, 0, 0);
            } else {
                s[1] = (f4_t){-1e30f, -1e30f, -1e30f, -1e30f};
            }

            // first V chunk issued early; vmcnt covered by the softmax below
            const unsigned short* vp = vth + (size_t)kt * 8192 + l16 * 32 + quad * 8;
            bf8_t vf[8];
            #pragma unroll
            for (int dt = 0; dt < 8; dt++)
                vf[dt] = *reinterpret_cast<const bf8_t*>(vp + dt * 512);

            float pv[2][4];
            float tm = -1e30f;
            #pragma unroll
            for (int t = 0; t < 2; t++)
                #pragma unroll
                for (int r = 0; r < 4; r++) {
                    int key = kBase + t * 16 + quad * 4 + r;
                    float sv = (key <= q_g) ? s[t][r] : -1e30f;
                    s[t][r] = sv;
                    tm = fmaxf(tm, sv);
                }
            tm = fmaxf(tm, __shfl_xor(tm, 16));
            tm = fmaxf(tm, __shfl_xor(tm, 32));
            float mnew = fmaxf(mrun, tm);
            float alpha = __expf(mrun - mnew);
            mrun = mnew;
            float ts = 0.f;
            #pragma unroll
            for (int t = 0; t < 2; t++)
                #pragma unroll
                for (int r = 0; r < 4; r++) {
                    float pe = __expf(s[t][r] - mnew);
                    pv[t][r] = pe;
                    ts += pe;
                }
            ts += __shfl_xor(ts, 16);
            ts += __shfl_xor(ts, 32);
            lrun = lrun * alpha + ts;
            if (__any(alpha != 1.0f)) {
                #pragma unroll
                for (int dt = 0; dt < 16; dt++) acc[dt] *= alpha;
            }

            #pragma unroll
            for (int t = 0; t < 2; t++) {
                union { unsigned short us[4]; unsigned long long u; } pk;
                #pragma unroll
                for (int r = 0; r < 4; r++) pk.us[r] = f2bf(pv[t][r]);
                *reinterpret_cast<unsigned long long*>(&Pw[l16 * 40 + t * 16 + quad * 4]) = pk.u;
            }
            asm volatile("s_waitcnt lgkmcnt(0)" ::: "memory");
            bf8_t pf = *reinterpret_cast<const bf8_t*>(&Pw[l16 * 40 + quad * 8]);
            #pragma unroll
            for (int dt = 0; dt < 8; dt++)
                acc[dt] = __builtin_amdgcn_mfma_f32_16x16x32_bf16(vf[dt], pf, acc[dt], 0, 0, 0);
            #pragma unroll
            for (int dt = 0; dt < 8; dt++)
                vf[dt] = *reinterpret_cast<const bf8_t*>(vp + (8 + dt) * 512);
            #pragma unroll
            for (int dt = 0; dt < 8; dt++)
                acc[8 + dt] = __builtin_amdgcn_mfma_f32_16x16x32_bf16(vf[dt], pf, acc[8 + dt], 0, 0, 0);
        }

        // ---- combine 4 wave-partials ----
        if (quad == 0) { MLb[w * 32 + l16] = mrun; MLb[w * 32 + 16 + l16] = lrun; }
        __syncthreads();
        float m0 = MLb[l16],      l0 = MLb[16 + l16];
        float m1 = MLb[32 + l16], l1 = MLb[48 + l16];
        float m2 = MLb[64 + l16], l2 = MLb[80 + l16];
        float m3 = MLb[96 + l16], l3 = MLb[112 + l16];
        float mg = fmaxf(fmaxf(m0, m1), fmaxf(m2, m3));
        float lg = l0 * __expf(m0 - mg) + l1 * __expf(m1 - mg)
                 + l2 * __expf(m2 - mg) + l3 * __expf(m3 - mg);
        float scale = __expf(mrun - mg);
        #pragma unroll
        for (int dt = 0; dt < 16; dt++) acc[dt] *= scale;

        if (w >= 2) {
            float* ob = &Ob[w - 2][l16][quad * 4];
            #pragma unroll
            for (int dt = 0; dt < 16; dt++)
                *reinterpret_cast<float4*>(ob + dt * 16) =
                    (float4){acc[dt][0], acc[dt][1], acc[dt][2], acc[dt][3]};
        }
        __syncthreads();
        if (w < 2) {
            const float* ob = &Ob[w][l16][quad * 4];
            #pragma unroll
            for (int dt = 0; dt < 16; dt++) {
                float4 v = *reinterpret_cast<const float4*>(ob + dt * 16);
                acc[dt][0] += v.x; acc[dt][1] += v.y;
                acc[dt][2] += v.z; acc[dt][3] += v.w;
            }
        }
        __syncthreads();
        if (w == 1) {
            float* ob = &Ob[0][l16][quad * 4];
            #pragma unroll
            for (int dt = 0; dt < 16; dt++)
                *reinterpret_cast<float4*>(ob + dt * 16) =
                    (float4){acc[dt][0], acc[dt][1], acc[dt][2], acc[dt][3]};
        }
        __syncthreads();
        if (w == 0) {
            const float* ob = &Ob[0][l16][quad * 4];
            float inv = 1.f / lg;
            float* dst = hout + hb + (size_t)q_g * D + quad * 4;
            #pragma unroll
            for (int dt = 0; dt < 16; dt++) {
                float4 v = *reinterpret_cast<const float4*>(ob + dt * 16);
                float4 o = {(acc[dt][0] + v.x) * inv, (acc[dt][1] + v.y) * inv,
                            (acc[dt][2] + v.z) * inv, (acc[dt][3] + v.w) * inv};
                *reinterpret_cast<float4*>(dst + dt * 16) = o;
            }
        }
        __syncthreads();
    }
}

// ---------------- equivariant path: one wave per q row ---------------------
__global__ __launch_bounds__(256) void equiv_kernel(
    const float* __restrict__ xsb, float* __restrict__ xout)
{
    __shared__ float xs[L * NCH];
    int head = blockIdx.y;
    int tid = threadIdx.x;
    const float4* src = reinterpret_cast<const float4*>(xsb + (size_t)head * L * NCH);
    #pragma unroll
    for (int it = 0; it < 3; it++)
        reinterpret_cast<float4*>(xs)[tid + it * 256] = src[tid + it * 256];
    __syncthreads();

    int w = tid >> 6, lane = tid & 63;
    int q = blockIdx.x * 4 + w;
    float xq0 = xs[q * 3 + 0], xq1 = xs[q * 3 + 1], xq2 = xs[q * 3 + 2];

    float m = 0.f;
    for (int k = lane; k < q; k += 64) {
        float d0 = xq0 - xs[k * 3 + 0];
        float d1 = xq1 - xs[k * 3 + 1];
        float d2 = xq2 - xs[k * 3 + 2];
        m = fmaxf(m, d0 * d0 + d1 * d1 + d2 * d2);
    }
    #pragma unroll
    for (int off = 1; off < 64; off <<= 1) m = fmaxf(m, __shfl_xor(m, off));

    float s0 = 0.f, s1 = 0.f, s2 = 0.f, sn = 0.f;
    for (int k = lane; k < q; k += 64) {
        float d0 = xq0 - xs[k * 3 + 0];
        float d1 = xq1 - xs[k * 3 + 1];
        float d2 = xq2 - xs[k * 3 + 2];
        float wgt = __expf(d0 * d0 + d1 * d1 + d2 * d2 - m);
        sn += wgt;
        s0 += wgt * xs[k * 3 + 0];
        s1 += wgt * xs[k * 3 + 1];
        s2 += wgt * xs[k * 3 + 2];
    }
    #pragma unroll
    for (int off = 1; off < 64; off <<= 1) {
        sn += __shfl_xor(sn, off);
        s0 += __shfl_xor(s0, off);
        s1 += __shfl_xor(s1, off);
        s2 += __shfl_xor(s2, off);
    }
    float Z = sn + __expf(-m);
    float inv = 0.5f / Z;
    if (lane == 0) {
        size_t ob = (size_t)head * L * NCH + (size_t)q * NCH;
        xout[ob + 0] = xq0 + inv * (s0 - sn * xq0);
        xout[ob + 1] = xq1 + inv * (s1 - sn * xq1);
        xout[ob + 2] = xq2 + inv * (s2 - sn * xq2);
    }
}

extern "C" void kernel_launch(void* const* d_in, const int* in_sizes, int n_in,
                              void* d_out, int out_size, void* d_ws, size_t ws_size,
                              hipStream_t stream)
{
    (void)in_sizes; (void)n_in; (void)out_size; (void)ws_size;
    const float* theta = (const float*)d_in[0];
    const float* xi    = (const float*)d_in[1];
    const float* edge  = (const float*)d_in[2];
    const float* Wq    = (const float*)d_in[3];
    const float* Wk    = (const float*)d_in[4];
    const float* Wv    = (const float*)d_in[5];

    float* out  = (float*)d_out;
    float* hout = out;
    float* xout = out + 8388608;
    float* eout = out + 8388608 + 98304;

    const size_t NE = 8388608;
    unsigned short* base = (unsigned short*)d_ws;
    unsigned short* qh = base;
    unsigned short* kh = base + NE;
    unsigned short* vt = base + 2 * NE;
    float* pe_d = (float*)(base + 3 * NE);           // 1024*256 floats
    float* xsb  = pe_d + L * D;                       // 32*1024*3 floats

    pe_d_kernel<<<(L * D + 255) / 256, 256, 0, stream>>>(pe_d);
    edge_kernel<<<(BATCH * L * EDIM + 255) / 256, 256, 0, stream>>>(edge, eout);
    xs_kernel<<<(HEADS * L * NCH + 255) / 256, 256, 0, stream>>>(xi, xsb);
    equiv_kernel<<<dim3(L / 4, HEADS), 256, 0, stream>>>(xsb, xout);
    qkv_mfma<<<dim3(6, 256), 256, 0, stream>>>(theta, pe_d, Wq, Wk, Wv,
                                               qh, kh, vt);
    attn_v5<<<1024, 256, 0, stream>>>(qh, kh, vt, hout);
}

// Round 7
// 301.569 us; speedup vs baseline: 1.0611x; 1.0143x over previous
//
#include <hip/hip_runtime.h>
#include <math.h>

#define L    1024
#define D    256
#define NCH  3
#define HEADS 32      // B*N
#define EDIM 112
#define BATCH 4

typedef __bf16 bf8_t __attribute__((ext_vector_type(8)));
typedef float  f4_t  __attribute__((ext_vector_type(4)));

// RNE float->bf16
__device__ inline unsigned short f2bf(float x) {
    unsigned u = __float_as_uint(x);
    u += 0x7FFFu + ((u >> 16) & 1u);
    return (unsigned short)(u >> 16);
}
__device__ inline float bf2f(unsigned short h) {
    return __uint_as_float(((unsigned)h) << 16);
}
// round-half-up pack of two floats to packed bf16 pair (P weights: err <=2^-9 rel)
__device__ inline unsigned packbf(float a, float b) {
    unsigned ua = __float_as_uint(a) + 0x8000u;
    unsigned ub = __float_as_uint(b) + 0x8000u;
    return (ua >> 16) | (ub & 0xFFFF0000u);
}

// ---------------- PE kernels (fp32; err ~1e-5 vs threshold 0.1) ------------
__global__ void pe_d_kernel(float* __restrict__ pe_d) {
    int idx = blockIdx.x * blockDim.x + threadIdx.x;
    if (idx >= L * D) return;
    int l = idx >> 8, i = idx & (D - 1);
    float expo = (float)(i & ~1) * (1.0f / (float)D);
    float ang = (float)l * __powf(10000.0f, -expo);
    pe_d[idx] = (i & 1) ? cosf(ang) : sinf(ang);
}

__global__ void edge_kernel(const float* __restrict__ edge, float* __restrict__ out) {
    int idx = blockIdx.x * blockDim.x + threadIdx.x;
    if (idx >= BATCH * L * EDIM) return;
    int i = idx % EDIM;
    int l = (idx / EDIM) % L;
    float expo = (float)(i & ~1) * (1.0f / (float)EDIM);
    float ang = (float)l * __powf(10000.0f, -expo);
    out[idx] = edge[idx] + ((i & 1) ? cosf(ang) : sinf(ang));
}

// xi + pe(n=3), computed once into xsb [32][1024][3]
__global__ void xs_kernel(const float* __restrict__ xi, float* __restrict__ xsb) {
    int idx = blockIdx.x * blockDim.x + threadIdx.x;
    if (idx >= HEADS * L * NCH) return;
    int c = idx % 3;
    int l = (idx / 3) & (L - 1);
    float ang = (c == 2) ? (float)l * 0.0021544347f : (float)l;  // 10000^(-2/3)
    float pe = (c == 1) ? cosf(ang) : sinf(ang);
    xsb[idx] = xi[idx] + pe;
}

// ---------------- one-time bf16 hi/lo conversion (kills qkv staging VALU) --
__global__ __launch_bounds__(256) void prep_x(
    const float* __restrict__ theta, const float* __restrict__ pe_d,
    unsigned short* __restrict__ xh, unsigned short* __restrict__ xl)
{
    int idx = (blockIdx.x * 256 + threadIdx.x) * 4;   // 8192 blocks exact
    float4 tv = *reinterpret_cast<const float4*>(&theta[idx]);
    float4 pv = *reinterpret_cast<const float4*>(&pe_d[idx & (L * D - 1)]);
    float xs4[4] = {tv.x + pv.x, tv.y + pv.y, tv.z + pv.z, tv.w + pv.w};
    union { unsigned short us[4]; unsigned long long u; } h, l;
    #pragma unroll
    for (int j = 0; j < 4; j++) {
        unsigned short hh = f2bf(xs4[j]);
        h.us[j] = hh;
        l.us[j] = f2bf(xs4[j] - bf2f(hh));
    }
    *reinterpret_cast<unsigned long long*>(&xh[idx]) = h.u;
    *reinterpret_cast<unsigned long long*>(&xl[idx]) = l.u;
}

__global__ __launch_bounds__(256) void prep_w(
    const float* __restrict__ Wq, const float* __restrict__ Wk,
    const float* __restrict__ Wv, unsigned short* __restrict__ wh)
{
    int idx = (blockIdx.x * 256 + threadIdx.x) * 4;   // 192 blocks exact
    const float* src = (idx < 65536) ? Wq : (idx < 131072 ? Wk : Wv);
    float4 v = *reinterpret_cast<const float4*>(&src[idx & 65535]);
    union { unsigned short us[4]; unsigned long long u; } h;
    h.us[0] = f2bf(v.x); h.us[1] = f2bf(v.y);
    h.us[2] = f2bf(v.z); h.us[3] = f2bf(v.w);
    *reinterpret_cast<unsigned long long*>(&wh[idx]) = h.u;
}

// ---------------- QKV projection: pure copy-stage + MFMA -------------------
// q,k: C^T = Wh*(Xh+Xl)^T -> b64 stores along e (hi only, q pre-scaled)
// v:   C   = Xh*Wh^T      -> tile-major vt[head][ktile32][e][key31]
__global__ __launch_bounds__(256) void qkv2(
    const unsigned short* __restrict__ xh, const unsigned short* __restrict__ xl,
    const unsigned short* __restrict__ wh,
    unsigned short* __restrict__ qh, unsigned short* __restrict__ kh,
    unsigned short* __restrict__ vt)
{
    __shared__ unsigned short XsH[128][40], XsL[128][40], WsH[128][40];

    int tid = threadIdx.x;
    int w = tid >> 6, lane = tid & 63;
    int quad = lane >> 4, l16 = lane & 15;
    int aoff = (w & 1) * 64, boff = (w >> 1) * 64;
    int rowBase = blockIdx.y * 128;
    int wsel = blockIdx.x >> 1;
    int eBase = (blockIdx.x & 1) * 128;
    const unsigned short* W = wh + wsel * 65536;

    f4_t acc[4][4];
    #pragma unroll
    for (int mi = 0; mi < 4; mi++)
        #pragma unroll
        for (int ni = 0; ni < 4; ni++) acc[mi][ni] = (f4_t){0.f, 0.f, 0.f, 0.f};

    int sr = tid >> 1;
    int ks = (tid & 1) * 16;

    for (int kt = 0; kt < 8; kt++) {
        int k0 = kt * 32 + ks;
        __syncthreads();
        {
            const unsigned short* xp = &xh[(size_t)(rowBase + sr) * D + k0];
            *reinterpret_cast<float4*>(&XsH[sr][ks])     = *reinterpret_cast<const float4*>(xp);
            *reinterpret_cast<float4*>(&XsH[sr][ks + 8]) = *reinterpret_cast<const float4*>(xp + 8);
            const unsigned short* lp = &xl[(size_t)(rowBase + sr) * D + k0];
            *reinterpret_cast<float4*>(&XsL[sr][ks])     = *reinterpret_cast<const float4*>(lp);
            *reinterpret_cast<float4*>(&XsL[sr][ks + 8]) = *reinterpret_cast<const float4*>(lp + 8);
            const unsigned short* wp = &W[(size_t)(eBase + sr) * D + k0];
            *reinterpret_cast<float4*>(&WsH[sr][ks])     = *reinterpret_cast<const float4*>(wp);
            *reinterpret_cast<float4*>(&WsH[sr][ks + 8]) = *reinterpret_cast<const float4*>(wp + 8);
        }
        __syncthreads();

        if (wsel < 2) {
            bf8_t aw[4];
            #pragma unroll
            for (int mi = 0; mi < 4; mi++)
                aw[mi] = *reinterpret_cast<const bf8_t*>(&WsH[aoff + mi * 16 + l16][quad * 8]);
            #pragma unroll
            for (int ni = 0; ni < 4; ni++) {
                bf8_t bxh = *reinterpret_cast<const bf8_t*>(&XsH[boff + ni * 16 + l16][quad * 8]);
                bf8_t bxl = *reinterpret_cast<const bf8_t*>(&XsL[boff + ni * 16 + l16][quad * 8]);
                #pragma unroll
                for (int mi = 0; mi < 4; mi++) {
                    acc[mi][ni] = __builtin_amdgcn_mfma_f32_16x16x32_bf16(aw[mi], bxh, acc[mi][ni], 0, 0, 0);
                    acc[mi][ni] = __builtin_amdgcn_mfma_f32_16x16x32_bf16(aw[mi], bxl, acc[mi][ni], 0, 0, 0);
                }
            }
        } else {
            bf8_t axh[4];
            #pragma unroll
            for (int mi = 0; mi < 4; mi++)
                axh[mi] = *reinterpret_cast<const bf8_t*>(&XsH[aoff + mi * 16 + l16][quad * 8]);
            #pragma unroll
            for (int ni = 0; ni < 4; ni++) {
                bf8_t bw = *reinterpret_cast<const bf8_t*>(&WsH[boff + ni * 16 + l16][quad * 8]);
                #pragma unroll
                for (int mi = 0; mi < 4; mi++)
                    acc[mi][ni] = __builtin_amdgcn_mfma_f32_16x16x32_bf16(axh[mi], bw, acc[mi][ni], 0, 0, 0);
            }
        }
    }

    if (wsel < 2) {
        float scale = (wsel == 0) ? 0.0625f : 1.0f;  // fold 1/sqrt(d) into q
        unsigned short* dh = (wsel == 0) ? qh : kh;
        #pragma unroll
        for (int mi = 0; mi < 4; mi++) {
            #pragma unroll
            for (int ni = 0; ni < 4; ni++) {
                int e0 = eBase + aoff + mi * 16 + quad * 4;
                size_t row = rowBase + boff + ni * 16 + l16;
                union { unsigned short us[4]; unsigned long long u; } ph;
                #pragma unroll
                for (int r = 0; r < 4; r++) ph.us[r] = f2bf(acc[mi][ni][r] * scale);
                *reinterpret_cast<unsigned long long*>(&dh[row * D + e0]) = ph.u;
            }
        }
    } else {
        #pragma unroll
        for (int mi = 0; mi < 4; mi++) {
            #pragma unroll
            for (int ni = 0; ni < 4; ni++) {
                int row0 = rowBase + aoff + mi * 16 + quad * 4;
                int e = eBase + boff + ni * 16 + l16;
                int head = row0 >> 10, kb = (row0 & 1023) >> 5, kk = row0 & 31;
                union { unsigned short us[4]; unsigned long long u; } pk;
                #pragma unroll
                for (int r = 0; r < 4; r++) pk.us[r] = f2bf(acc[mi][ni][r]);
                *reinterpret_cast<unsigned long long*>(
                    &vt[((size_t)(head * 32 + kb)) * 8192 + (size_t)e * 32 + kk]) = pk.u;
            }
        }
    }
}

// ---------------- K-split flash attention, K-prefetch pipeline -------------
// Block = (head, pair u/63-u), 4 waves strided over kt (mod 4).
// Next tile's K t0 fragments prefetched into regs during softmax+PV; sticky
// overshoot max makes the 64-mul acc rescale rare; mask only on last tile.
__global__ __launch_bounds__(256) void attn_v6(
    const unsigned short* __restrict__ qh, const unsigned short* __restrict__ kh,
    const unsigned short* __restrict__ vt, float* __restrict__ hout)
{
    __shared__ unsigned short Pb[4][640];
    __shared__ float Ob[2][16][268];
    __shared__ float MLb[128];

    int tid = threadIdx.x;
    int w = tid >> 6, lane = tid & 63;
    int quad = lane >> 4, l16 = lane & 15;
    int b = blockIdx.x;
    int head = b & 31, p = b >> 5;          // same head -> same XCD (b%8 const)
    size_t hb = (size_t)head * (L * D);
    const unsigned short* vth = vt + (size_t)head * (32 * 8192);
    unsigned short* Pw = Pb[w];

    #pragma unroll 1
    for (int half = 0; half < 2; half++) {
        int u = half ? (63 - p) : p;         // pair sums to 34 kt-tiles
        int q_g = u * 16 + l16;
        int rmax = u * 16 + 15;

        bf8_t qf[8];
        {
            const unsigned short* ph = qh + hb + (size_t)q_g * D + quad * 8;
            #pragma unroll
            for (int c = 0; c < 8; c++) qf[c] = *reinterpret_cast<const bf8_t*>(ph + c * 32);
        }

        f4_t acc[16];
        #pragma unroll
        for (int i = 0; i < 16; i++) acc[i] = (f4_t){0.f, 0.f, 0.f, 0.f};
        float mrun = -1e30f, lrun = 0.f;
        int nkt = (u >> 1) + 1;

        bf8_t kfp[8];                        // prefetched K t0 fragments
        if (w < nkt) {
            const unsigned short* kp = kh + hb + (size_t)(w * 32 + l16) * D + quad * 8;
            #pragma unroll
            for (int c = 0; c < 8; c++) kfp[c] = *reinterpret_cast<const bf8_t*>(kp + c * 32);
        }

        #pragma unroll 1
        for (int kt = w; kt < nkt; kt += 4) {
            int kBase = kt * 32;

            f4_t s0 = (f4_t){0.f, 0.f, 0.f, 0.f};
            #pragma unroll
            for (int c = 0; c < 8; c++)
                s0 = __builtin_amdgcn_mfma_f32_16x16x32_bf16(kfp[c], qf[c], s0, 0, 0, 0);

            f4_t s1;
            if (kBase + 16 <= rmax) {
                s1 = (f4_t){0.f, 0.f, 0.f, 0.f};
                const unsigned short* kp = kh + hb + (size_t)(kBase + 16 + l16) * D + quad * 8;
                bf8_t kf1[8];
                #pragma unroll
                for (int c = 0; c < 8; c++) kf1[c] = *reinterpret_cast<const bf8_t*>(kp + c * 32);
                #pragma unroll
                for (int c = 0; c < 8; c++)
                    s1 = __builtin_amdgcn_mfma_f32_16x16x32_bf16(kf1[c], qf[c], s1, 0, 0, 0);
            } else {
                s1 = (f4_t){-1e30f, -1e30f, -1e30f, -1e30f};
            }

            // all 16 V fragments in flight across the softmax
            const unsigned short* vp = vth + (size_t)kt * 8192 + l16 * 32 + quad * 8;
            bf8_t vf[16];
            #pragma unroll
            for (int dt = 0; dt < 16; dt++)
                vf[dt] = *reinterpret_cast<const bf8_t*>(vp + dt * 512);

            // prefetch next iteration's K t0 (lands during softmax+PV)
            if (kt + 4 < nkt) {
                const unsigned short* kp = kh + hb + (size_t)((kt + 4) * 32 + l16) * D + quad * 8;
                #pragma unroll
                for (int c = 0; c < 8; c++) kfp[c] = *reinterpret_cast<const bf8_t*>(kp + c * 32);
            }

            if (kt == nkt - 1) {             // only the last tile can cross diagonal
                #pragma unroll
                for (int r = 0; r < 4; r++) {
                    if (kBase + quad * 4 + r > q_g)      s0[r] = -1e30f;
                    if (kBase + 16 + quad * 4 + r > q_g) s1[r] = -1e30f;
                }
            }

            float tm = fmaxf(fmaxf(fmaxf(s0[0], s0[1]), fmaxf(s0[2], s0[3])),
                             fmaxf(fmaxf(s1[0], s1[1]), fmaxf(s1[2], s1[3])));
            tm = fmaxf(tm, __shfl_xor(tm, 16));
            tm = fmaxf(tm, __shfl_xor(tm, 32));

            float alpha = 1.0f, mnew = mrun;
            if (__any(tm > mrun)) {
                mnew = fmaxf(mrun, tm + 3.0f);   // overshoot: future rescales rare
                alpha = __expf(mrun - mnew);
                mrun = mnew;
            }
            float p0[4], p1[4];
            float ts = 0.f;
            #pragma unroll
            for (int r = 0; r < 4; r++) { p0[r] = __expf(s0[r] - mnew); ts += p0[r]; }
            #pragma unroll
            for (int r = 0; r < 4; r++) { p1[r] = __expf(s1[r] - mnew); ts += p1[r]; }
            ts += __shfl_xor(ts, 16);
            ts += __shfl_xor(ts, 32);
            lrun = lrun * alpha + ts;
            if (__any(alpha != 1.0f)) {
                #pragma unroll
                for (int dt = 0; dt < 16; dt++) acc[dt] *= alpha;
            }

            uint2 pw0, pw1;
            pw0.x = packbf(p0[0], p0[1]); pw0.y = packbf(p0[2], p0[3]);
            pw1.x = packbf(p1[0], p1[1]); pw1.y = packbf(p1[2], p1[3]);
            *reinterpret_cast<uint2*>(&Pw[l16 * 40 + quad * 4]) = pw0;
            *reinterpret_cast<uint2*>(&Pw[l16 * 40 + 16 + quad * 4]) = pw1;
            asm volatile("s_waitcnt lgkmcnt(0)" ::: "memory");
            bf8_t pf = *reinterpret_cast<const bf8_t*>(&Pw[l16 * 40 + quad * 8]);
            #pragma unroll
            for (int dt = 0; dt < 16; dt++)
                acc[dt] = __builtin_amdgcn_mfma_f32_16x16x32_bf16(vf[dt], pf, acc[dt], 0, 0, 0);
        }

        // ---- combine 4 wave-partials ----
        if (quad == 0) { MLb[w * 32 + l16] = mrun; MLb[w * 32 + 16 + l16] = lrun; }
        __syncthreads();
        float m0 = MLb[l16],      l0 = MLb[16 + l16];
        float m1 = MLb[32 + l16], l1 = MLb[48 + l16];
        float m2 = MLb[64 + l16], l2 = MLb[80 + l16];
        float m3 = MLb[96 + l16], l3 = MLb[112 + l16];
        float mg = fmaxf(fmaxf(m0, m1), fmaxf(m2, m3));
        float lg = l0 * __expf(m0 - mg) + l1 * __expf(m1 - mg)
                 + l2 * __expf(m2 - mg) + l3 * __expf(m3 - mg);
        float scale = __expf(mrun - mg);
        #pragma unroll
        for (int dt = 0; dt < 16; dt++) acc[dt] *= scale;

        if (w >= 2) {
            float* ob = &Ob[w - 2][l16][quad * 4];
            #pragma unroll
            for (int dt = 0; dt < 16; dt++)
                *reinterpret_cast<float4*>(ob + dt * 16) =
                    (float4){acc[dt][0], acc[dt][1], acc[dt][2], acc[dt][3]};
        }
        __syncthreads();
        if (w < 2) {
            const float* ob = &Ob[w][l16][quad * 4];
            #pragma unroll
            for (int dt = 0; dt < 16; dt++) {
                float4 v = *reinterpret_cast<const float4*>(ob + dt * 16);
                acc[dt][0] += v.x; acc[dt][1] += v.y;
                acc[dt][2] += v.z; acc[dt][3] += v.w;
            }
        }
        __syncthreads();
        if (w == 1) {
            float* ob = &Ob[0][l16][quad * 4];
            #pragma unroll
            for (int dt = 0; dt < 16; dt++)
                *reinterpret_cast<float4*>(ob + dt * 16) =
                    (float4){acc[dt][0], acc[dt][1], acc[dt][2], acc[dt][3]};
        }
        __syncthreads();
        if (w == 0) {
            const float* ob = &Ob[0][l16][quad * 4];
            float inv = 1.f / lg;
            float* dst = hout + hb + (size_t)q_g * D + quad * 4;
            #pragma unroll
            for (int dt = 0; dt < 16; dt++) {
                float4 v = *reinterpret_cast<const float4*>(ob + dt * 16);
                float4 o = {(acc[dt][0] + v.x) * inv, (acc[dt][1] + v.y) * inv,
                            (acc[dt][2] + v.z) * inv, (acc[dt][3] + v.w) * inv};
                *reinterpret_cast<float4*>(dst + dt * 16) = o;
            }
        }
        __syncthreads();
    }
}

// ---------------- equivariant path: single-pass online softmax -------------
__global__ __launch_bounds__(256) void equiv_kernel(
    const float* __restrict__ xsb, float* __restrict__ xout)
{
    __shared__ float xs[L * NCH];
    int head = blockIdx.y;
    int tid = threadIdx.x;
    const float4* src = reinterpret_cast<const float4*>(xsb + (size_t)head * L * NCH);
    #pragma unroll
    for (int it = 0; it < 3; it++)
        reinterpret_cast<float4*>(xs)[tid + it * 256] = src[tid + it * 256];
    __syncthreads();

    int w = tid >> 6, lane = tid & 63;
    int q = blockIdx.x * 4 + w;
    float xq0 = xs[q * 3 + 0], xq1 = xs[q * 3 + 1], xq2 = xs[q * 3 + 2];

    float m = 0.f, sn = 0.f, s0 = 0.f, s1 = 0.f, s2 = 0.f;   // m=0 covers diag
    for (int k = lane; k < q; k += 64) {
        float d0 = xq0 - xs[k * 3 + 0];
        float d1 = xq1 - xs[k * 3 + 1];
        float d2 = xq2 - xs[k * 3 + 2];
        float sq = d0 * d0 + d1 * d1 + d2 * d2;
        if (sq > m) {                         // sticky overshoot, per-lane
            float sc = __expf(m - sq - 3.0f);
            m = sq + 3.0f;
            sn *= sc; s0 *= sc; s1 *= sc; s2 *= sc;
        }
        float wgt = __expf(sq - m);
        sn += wgt;
        s0 += wgt * xs[k * 3 + 0];
        s1 += wgt * xs[k * 3 + 1];
        s2 += wgt * xs[k * 3 + 2];
    }
    float mg = m;
    #pragma unroll
    for (int off = 1; off < 64; off <<= 1) mg = fmaxf(mg, __shfl_xor(mg, off));
    float sc = __expf(m - mg);
    sn *= sc; s0 *= sc; s1 *= sc; s2 *= sc;
    #pragma unroll
    for (int off = 1; off < 64; off <<= 1) {
        sn += __shfl_xor(sn, off);
        s0 += __shfl_xor(s0, off);
        s1 += __shfl_xor(s1, off);
        s2 += __shfl_xor(s2, off);
    }
    float Z = sn + __expf(-mg);               // diagonal term
    float inv = 0.5f / Z;
    if (lane == 0) {
        size_t ob = (size_t)head * L * NCH + (size_t)q * NCH;
        xout[ob + 0] = xq0 + inv * (s0 - sn * xq0);
        xout[ob + 1] = xq1 + inv * (s1 - sn * xq1);
        xout[ob + 2] = xq2 + inv * (s2 - sn * xq2);
    }
}

extern "C" void kernel_launch(void* const* d_in, const int* in_sizes, int n_in,
                              void* d_out, int out_size, void* d_ws, size_t ws_size,
                              hipStream_t stream)
{
    (void)in_sizes; (void)n_in; (void)out_size; (void)ws_size;
    const float* theta = (const float*)d_in[0];
    const float* xi    = (const float*)d_in[1];
    const float* edge  = (const float*)d_in[2];
    const float* Wq    = (const float*)d_in[3];
    const float* Wk    = (const float*)d_in[4];
    const float* Wv    = (const float*)d_in[5];

    float* out  = (float*)d_out;
    float* hout = out;
    float* xout = out + 8388608;
    float* eout = out + 8388608 + 98304;

    const size_t NE = 8388608;
    unsigned short* base = (unsigned short*)d_ws;
    unsigned short* qh = base;
    unsigned short* kh = base + NE;
    unsigned short* vt = base + 2 * NE;
    unsigned short* xh = base + 3 * NE;
    unsigned short* xl = base + 4 * NE;
    unsigned short* wh = base + 5 * NE;              // 3*65536 shorts
    float* pe_d = (float*)(base + 5 * NE + 196608);  // 1024*256 floats
    float* xsb  = pe_d + L * D;                      // 32*1024*3 floats

    pe_d_kernel<<<(L * D + 255) / 256, 256, 0, stream>>>(pe_d);
    prep_x<<<8192, 256, 0, stream>>>(theta, pe_d, xh, xl);
    prep_w<<<192, 256, 0, stream>>>(Wq, Wk, Wv, wh);
    edge_kernel<<<(BATCH * L * EDIM + 255) / 256, 256, 0, stream>>>(edge, eout);
    xs_kernel<<<(HEADS * L * NCH + 255) / 256, 256, 0, stream>>>(xi, xsb);
    equiv_kernel<<<dim3(L / 4, HEADS), 256, 0, stream>>>(xsb, xout);
    qkv2<<<dim3(6, 256), 256, 0, stream>>>(xh, xl, wh, qh, kh, vt);
    attn_v6<<<1024, 256, 0, stream>>>(qh, kh, vt, hout);
}